// Round 4
// baseline (905.431 us; speedup 1.0000x reference)
//
#include <hip/hip_runtime.h>

#define NN 50000
#define NE 600000
#define HD 128
#define NL 4
#define NB 256
#define NO 10
#define BN_EPS 1e-5f

typedef short bf16x8 __attribute__((ext_vector_type(8)));
typedef float f32x4 __attribute__((ext_vector_type(4)));

__device__ __forceinline__ unsigned short f2bf(float f) {
    union { float f; unsigned int u; } x; x.f = f;
    unsigned int u = x.u;
    unsigned int r = (u + 0x7FFFu + ((u >> 16) & 1u)) >> 16;  // RNE
    return (unsigned short)r;
}
__device__ __forceinline__ float bf2f(unsigned short s) {
    union { unsigned int u; float f; } x; x.u = ((unsigned int)s) << 16;
    return x.f;
}

// ---------------- CSR build ----------------

__global__ void hist_kernel(const int* __restrict__ col, int* __restrict__ cnt, int e) {
    int i = blockIdx.x * blockDim.x + threadIdx.x;
    if (i < e) atomicAdd(&cnt[col[i]], 1);
}

// scan over M=N+1 elements + fused dinv
__global__ void scan1_kernel(const int* __restrict__ cnt, int* __restrict__ outp,
                             int* __restrict__ bsums, float* __restrict__ dinv,
                             int M, int n) {
    __shared__ int s[256];
    int tid = threadIdx.x;
    int base = blockIdx.x * 1024 + tid * 4;
    int v[4];
#pragma unroll
    for (int j = 0; j < 4; ++j) {
        int idx = base + j;
        v[j] = (idx < n) ? cnt[idx] : 0;
        if (idx < n) dinv[idx] = rsqrtf((float)(v[j] + 1));  // +1 self-loop
    }
    int tot = v[0] + v[1] + v[2] + v[3];
    s[tid] = tot;
    __syncthreads();
    for (int off = 1; off < 256; off <<= 1) {
        int x = (tid >= off) ? s[tid - off] : 0;
        __syncthreads();
        s[tid] += x;
        __syncthreads();
    }
    int run = (tid == 0) ? 0 : s[tid - 1];
#pragma unroll
    for (int j = 0; j < 4; ++j) {
        int idx = base + j;
        if (idx < M) outp[idx] = run;
        run += v[j];
    }
    if (tid == 255) bsums[blockIdx.x] = s[255];
}

__global__ void scan2_kernel(int* bsums, int nb) {
    if (threadIdx.x == 0 && blockIdx.x == 0) {
        int acc = 0;
        for (int i = 0; i < nb; ++i) { int v = bsums[i]; bsums[i] = acc; acc += v; }
    }
}

__global__ void scan3_kernel(int* __restrict__ outp, const int* __restrict__ bsums, int M) {
    int i = blockIdx.x * blockDim.x + threadIdx.x;
    if (i < M) outp[i] += bsums[i >> 10];
}

__global__ void place_kernel(const int* __restrict__ row, const int* __restrict__ col,
                             const float* __restrict__ dinv, const int* __restrict__ rp,
                             int* __restrict__ fill, int2* __restrict__ csr, int e) {
    int i = blockIdx.x * blockDim.x + threadIdx.x;
    if (i < e) {
        int r = row[i], c = col[i];
        int pos = atomicAdd(&fill[c], 1);
        int idx = rp[c] + pos;
        csr[idx] = make_int2(r, __float_as_int(dinv[r] * dinv[c]));
    }
}

// ---------------- weight transpose+convert: Wt[m][n][k] = bf16(Wsrc_m[k][n]) ----------------
__global__ void wconv_kernel(const float* __restrict__ W_enc, const float* __restrict__ W,
                             unsigned short* __restrict__ Wt) {
    int i = blockIdx.x * blockDim.x + threadIdx.x;
    if (i >= 5 * 16384) return;
    int m = i >> 14;
    int r = (i >> 7) & 127;  // dest row = n
    int k = i & 127;         // dest col = k
    const float* src = (m == 0) ? W_enc : (W + (size_t)(m - 1) * 16384);
    Wt[i] = f2bf(src[k * 128 + r]);
}

// ---------------- MFMA GEMM: C[n x 128] = A[n x 128] @ W[128 x 128] (+bias), C bf16 ----------------
// AMODE: 0 = fp32 A, 1 = bf16 A, 2 = fp32 A with fused BN(scale,shift)+ReLU
template <int AMODE>
__global__ __launch_bounds__(256) void gemm128_mfma(const void* __restrict__ Ap,
                                                    const unsigned short* __restrict__ Wt,
                                                    const float* __restrict__ bias,
                                                    const float* __restrict__ bnp,
                                                    unsigned short* __restrict__ Cp,
                                                    int nrows) {
    int wave = threadIdx.x >> 6;
    int lane = threadIdx.x & 63;
    int r16 = lane & 15;
    int kg = lane >> 4;
    int rowBase = blockIdx.x * 64 + wave * 16;
    int row = rowBase + r16;
    bool valid = row < nrows;

    bf16x8 afr[4];
#pragma unroll
    for (int s = 0; s < 4; ++s) {
        bf16x8 tt = {};
        int c0 = s * 32 + kg * 8;
        if constexpr (AMODE == 1) {
            const unsigned short* A = (const unsigned short*)Ap;
            if (valid) tt = *(const bf16x8*)&A[(size_t)row * 128 + c0];
        } else if constexpr (AMODE == 0) {
            const float* A = (const float*)Ap;
            if (valid) {
                const float* p = &A[(size_t)row * 128 + c0];
                float4 u0 = *(const float4*)p;
                float4 u1 = *(const float4*)(p + 4);
                tt[0] = (short)f2bf(u0.x); tt[1] = (short)f2bf(u0.y);
                tt[2] = (short)f2bf(u0.z); tt[3] = (short)f2bf(u0.w);
                tt[4] = (short)f2bf(u1.x); tt[5] = (short)f2bf(u1.y);
                tt[6] = (short)f2bf(u1.z); tt[7] = (short)f2bf(u1.w);
            }
        } else {
            const float* A = (const float*)Ap;
            if (valid) {
                const float* p = &A[(size_t)row * 128 + c0];
                float4 u0 = *(const float4*)p;
                float4 u1 = *(const float4*)(p + 4);
                float4 s0 = *(const float4*)&bnp[c0];
                float4 s1 = *(const float4*)&bnp[c0 + 4];
                float4 h0 = *(const float4*)&bnp[128 + c0];
                float4 h1 = *(const float4*)&bnp[128 + c0 + 4];
                tt[0] = (short)f2bf(fmaxf(u0.x * s0.x + h0.x, 0.f));
                tt[1] = (short)f2bf(fmaxf(u0.y * s0.y + h0.y, 0.f));
                tt[2] = (short)f2bf(fmaxf(u0.z * s0.z + h0.z, 0.f));
                tt[3] = (short)f2bf(fmaxf(u0.w * s0.w + h0.w, 0.f));
                tt[4] = (short)f2bf(fmaxf(u1.x * s1.x + h1.x, 0.f));
                tt[5] = (short)f2bf(fmaxf(u1.y * s1.y + h1.y, 0.f));
                tt[6] = (short)f2bf(fmaxf(u1.z * s1.z + h1.z, 0.f));
                tt[7] = (short)f2bf(fmaxf(u1.w * s1.w + h1.w, 0.f));
            }
        }
        afr[s] = tt;
    }

    f32x4 acc[8];
#pragma unroll
    for (int n = 0; n < 8; ++n) acc[n] = (f32x4){0.f, 0.f, 0.f, 0.f};

#pragma unroll
    for (int n = 0; n < 8; ++n) {
        const unsigned short* wp = &Wt[(size_t)(n * 16 + r16) * 128 + kg * 8];
#pragma unroll
        for (int s = 0; s < 4; ++s) {
            bf16x8 bfr = *(const bf16x8*)&wp[s * 32];
            acc[n] = __builtin_amdgcn_mfma_f32_16x16x32_bf16(afr[s], bfr, acc[n], 0, 0, 0);
        }
    }

    // C/D: lane holds rows kg*4+i, col r16 (within tile)
#pragma unroll
    for (int n = 0; n < 8; ++n) {
        int col = n * 16 + r16;
        float bv = bias ? bias[col] : 0.f;
#pragma unroll
        for (int i = 0; i < 4; ++i) {
            int orow = rowBase + kg * 4 + i;
            if (orow < nrows)
                Cp[(size_t)orow * 128 + col] = f2bf(acc[n][i] + bv);
        }
    }
}

// ---------------- Aggregation: agg[i] = b + dinv_i^2 * t[i] + sum_e w_e * t[src_e] ----------------
__global__ __launch_bounds__(256) void aggregate_kernel(const unsigned short* __restrict__ t,
                                                        const int* __restrict__ rp,
                                                        const int2* __restrict__ csr,
                                                        const float* __restrict__ dinv,
                                                        const float* __restrict__ bvec,
                                                        float* __restrict__ agg, int n) {
    int wid = blockIdx.x * 4 + (threadIdx.x >> 6);
    int lane = threadIdx.x & 63;
    if (wid >= n) return;
    int c = lane * 2;
    float di = dinv[wid];
    float sw = di * di;
    unsigned int u = *(const unsigned int*)&t[(size_t)wid * 128 + c];
    float2 acc;
    acc.x = sw * bf2f((unsigned short)(u & 0xffff)) + bvec[c];
    acc.y = sw * bf2f((unsigned short)(u >> 16)) + bvec[c + 1];
    int e = rp[wid], e1 = rp[wid + 1];
    for (; e + 3 < e1; e += 4) {
        int2 ew0 = csr[e], ew1 = csr[e + 1], ew2 = csr[e + 2], ew3 = csr[e + 3];
        unsigned int u0 = *(const unsigned int*)&t[(size_t)ew0.x * 128 + c];
        unsigned int u1 = *(const unsigned int*)&t[(size_t)ew1.x * 128 + c];
        unsigned int u2 = *(const unsigned int*)&t[(size_t)ew2.x * 128 + c];
        unsigned int u3 = *(const unsigned int*)&t[(size_t)ew3.x * 128 + c];
        float w0 = __int_as_float(ew0.y), w1 = __int_as_float(ew1.y);
        float w2 = __int_as_float(ew2.y), w3 = __int_as_float(ew3.y);
        acc.x += w0 * bf2f((unsigned short)(u0 & 0xffff)) + w1 * bf2f((unsigned short)(u1 & 0xffff));
        acc.y += w0 * bf2f((unsigned short)(u0 >> 16)) + w1 * bf2f((unsigned short)(u1 >> 16));
        acc.x += w2 * bf2f((unsigned short)(u2 & 0xffff)) + w3 * bf2f((unsigned short)(u3 & 0xffff));
        acc.y += w2 * bf2f((unsigned short)(u2 >> 16)) + w3 * bf2f((unsigned short)(u3 >> 16));
    }
    for (; e < e1; ++e) {
        int2 ew = csr[e];
        unsigned int u0 = *(const unsigned int*)&t[(size_t)ew.x * 128 + c];
        float w0 = __int_as_float(ew.y);
        acc.x += w0 * bf2f((unsigned short)(u0 & 0xffff));
        acc.y += w0 * bf2f((unsigned short)(u0 >> 16));
    }
    *(float2*)&agg[(size_t)wid * 128 + c] = acc;
}

// ---------------- BatchNorm stats + finalize (wide grid, f32x4, last-block finalize) ----------------
#define BN_BLOCKS 1024
__global__ __launch_bounds__(256) void bn_stats_kernel(const float* __restrict__ agg,
                                                       float* __restrict__ sums,
                                                       int* __restrict__ counter,
                                                       const float* __restrict__ gamma,
                                                       const float* __restrict__ beta,
                                                       float* __restrict__ bnp, int n) {
    int tid = threadIdx.x;
    int c4 = tid & 31, rs = tid >> 5;
    f32x4 s = {0.f, 0.f, 0.f, 0.f}, q = {0.f, 0.f, 0.f, 0.f};
    for (int r = blockIdx.x * 8 + rs; r < n; r += BN_BLOCKS * 8) {
        f32x4 v = *(const f32x4*)&agg[(size_t)r * 128 + c4 * 4];
        s += v;
        q += v * v;
    }
    __shared__ f32x4 ls[256], lq[256];
    __shared__ int lastflag;
    ls[tid] = s;
    lq[tid] = q;
    __syncthreads();
    if (tid < 32) {
        f32x4 ss = ls[tid], qq = lq[tid];
#pragma unroll
        for (int j = 1; j < 8; ++j) { ss += ls[tid + 32 * j]; qq += lq[tid + 32 * j]; }
#pragma unroll
        for (int k = 0; k < 4; ++k) {
            atomicAdd(&sums[tid * 4 + k], ss[k]);
            atomicAdd(&sums[128 + tid * 4 + k], qq[k]);
        }
    }
    __threadfence();
    __syncthreads();
    if (tid == 0) {
        int old = atomicAdd(counter, 1);
        lastflag = (old == BN_BLOCKS - 1);
    }
    __syncthreads();
    if (lastflag && tid < 128) {
        float fn = (float)n;
        float ss = atomicAdd(&sums[tid], 0.f);
        float qq = atomicAdd(&sums[128 + tid], 0.f);
        float mean = ss / fn;
        float var = fmaxf(qq / fn - mean * mean, 0.f);
        float sc = gamma[tid] * rsqrtf(var + BN_EPS);
        bnp[tid] = sc;
        bnp[128 + tid] = beta[tid] - mean * sc;
        // self-reset for next layer / next graph replay
        sums[tid] = 0.f;
        sums[128 + tid] = 0.f;
        if (tid == 0) *counter = 0;
    }
}

// ---------------- Pool (BN+ReLU fused) + classifier, one block per graph ----------------
__global__ __launch_bounds__(256) void pool_cls_kernel(const float* __restrict__ agg,
                                                       const float* __restrict__ bnp,
                                                       const int* __restrict__ batch,
                                                       const float* __restrict__ Wc,
                                                       const float* __restrict__ bc,
                                                       float* __restrict__ out, int n) {
    int b = blockIdx.x;  // graph id, 0..NB-1
    int tid = threadIdx.x;
    // row range of graph b in sorted batch
    int lo = 0, hi = n;
    while (lo < hi) { int mid = (lo + hi) >> 1; if (batch[mid] < b) lo = mid + 1; else hi = mid; }
    int start = lo;
    hi = n;
    while (lo < hi) { int mid = (lo + hi) >> 1; if (batch[mid] <= b) lo = mid + 1; else hi = mid; }
    int end = lo;

    int c4 = tid & 31, rs = tid >> 5;
    f32x4 sc = *(const f32x4*)&bnp[c4 * 4];
    f32x4 sh = *(const f32x4*)&bnp[128 + c4 * 4];
    f32x4 acc = {0.f, 0.f, 0.f, 0.f};
    for (int r = start + rs; r < end; r += 8) {
        f32x4 v = *(const f32x4*)&agg[(size_t)r * 128 + c4 * 4];
        f32x4 y = v * sc + sh;
#pragma unroll
        for (int k = 0; k < 4; ++k) y[k] = fmaxf(y[k], 0.f);
        acc += y;
    }
    __shared__ f32x4 ls[256];
    __shared__ float g[128];
    ls[tid] = acc;
    __syncthreads();
    if (tid < 32) {
        f32x4 ss = ls[tid];
#pragma unroll
        for (int j = 1; j < 8; ++j) ss += ls[tid + 32 * j];
        float invc = 1.0f / fmaxf((float)(end - start), 1.0f);
#pragma unroll
        for (int k = 0; k < 4; ++k) g[tid * 4 + k] = ss[k] * invc;
    }
    __syncthreads();
    if (tid < NO) {
        float s = bc[tid];
        for (int c = 0; c < 128; ++c) s += g[c] * Wc[c * NO + tid];
        out[b * NO + tid] = s;
    }
}

// ---------------- host launch ----------------
extern "C" void kernel_launch(void* const* d_in, const int* in_sizes, int n_in,
                              void* d_out, int out_size, void* d_ws, size_t ws_size,
                              hipStream_t stream) {
    const float* x      = (const float*)d_in[0];
    const int*   eidx   = (const int*)d_in[1];
    const int*   batch  = (const int*)d_in[2];
    const float* W_enc  = (const float*)d_in[3];
    const float* b_enc  = (const float*)d_in[4];
    const float* W      = (const float*)d_in[5];
    const float* b      = (const float*)d_in[6];
    const float* gamma  = (const float*)d_in[7];
    const float* beta   = (const float*)d_in[8];
    const float* W_cls  = (const float*)d_in[9];
    const float* b_cls  = (const float*)d_in[10];
    float* out = (float*)d_out;

    const int* erow = eidx;
    const int* ecol = eidx + NE;

    // workspace layout
    float* agg    = (float*)d_ws;                    // NN*HD fp32
    float* dinv   = agg + (size_t)NN * HD;           // NN
    float* bnsums = dinv + NN;                       // 256
    int*   bncnt  = (int*)(bnsums + 256);            // 4 ints (1 used)
    float* bnp    = (float*)(bncnt + 4);             // 256
    int2*  csr    = (int2*)(bnp + 256);              // NE int2
    unsigned short* h  = (unsigned short*)(csr + NE);   // NN*HD bf16
    unsigned short* t  = h + (size_t)NN * HD;           // NN*HD bf16
    unsigned short* Wt = t + (size_t)NN * HD;           // 5*16384 bf16
    int* cnt      = (int*)(Wt + 5 * 16384);          // NN
    int* fill     = cnt + NN;                        // NN (adjacent -> one memset)
    int* rp       = fill + NN;                       // NN+1
    int* bsums    = rp + NN + 1;                     // 64

    hipMemsetAsync(cnt, 0, 2 * NN * sizeof(int), stream);
    hipMemsetAsync(bnsums, 0, 256 * sizeof(float) + 4 * sizeof(int), stream);

    // CSR build (once; reused across layers)
    hist_kernel<<<(NE + 255) / 256, 256, 0, stream>>>(ecol, cnt, NE);
    int M = NN + 1;
    int nscan = (M + 1023) / 1024;
    scan1_kernel<<<nscan, 256, 0, stream>>>(cnt, rp, bsums, dinv, M, NN);
    scan2_kernel<<<1, 64, 0, stream>>>(bsums, nscan);
    scan3_kernel<<<(M + 255) / 256, 256, 0, stream>>>(rp, bsums, M);
    place_kernel<<<(NE + 255) / 256, 256, 0, stream>>>(erow, ecol, dinv, rp, fill, csr, NE);

    // weights -> bf16 transposed
    wconv_kernel<<<(5 * 16384 + 255) / 256, 256, 0, stream>>>(W_enc, W, Wt);

    int gemmBlocks = (NN + 63) / 64;
    // encoder: x fp32 -> h bf16
    gemm128_mfma<0><<<gemmBlocks, 256, 0, stream>>>(x, Wt, b_enc, nullptr, h, NN);

    for (int l = 0; l < NL; ++l) {
        if (l == 0)
            gemm128_mfma<1><<<gemmBlocks, 256, 0, stream>>>(
                h, Wt + (size_t)(l + 1) * 16384, nullptr, nullptr, t, NN);
        else
            gemm128_mfma<2><<<gemmBlocks, 256, 0, stream>>>(
                agg, Wt + (size_t)(l + 1) * 16384, nullptr, bnp, t, NN);
        aggregate_kernel<<<(NN + 3) / 4, 256, 0, stream>>>(t, rp, csr, dinv,
                                                           b + (size_t)l * HD, agg, NN);
        bn_stats_kernel<<<BN_BLOCKS, 256, 0, stream>>>(agg, bnsums, bncnt,
                                                       gamma + (size_t)l * HD,
                                                       beta + (size_t)l * HD, bnp, NN);
    }

    pool_cls_kernel<<<NB, 256, 0, stream>>>(agg, bnp, batch, W_cls, b_cls, out, NN);
}

// Round 5
// 574.180 us; speedup vs baseline: 1.5769x; 1.5769x over previous
//
#include <hip/hip_runtime.h>

#define NN 50000
#define NE 600000
#define HD 128
#define NL 4
#define NB 256
#define NO 10
#define BN_EPS 1e-5f

typedef short bf16x8 __attribute__((ext_vector_type(8)));
typedef float f32x4 __attribute__((ext_vector_type(4)));

__device__ __forceinline__ unsigned short f2bf(float f) {
    union { float f; unsigned int u; } x; x.f = f;
    unsigned int u = x.u;
    unsigned int r = (u + 0x7FFFu + ((u >> 16) & 1u)) >> 16;  // RNE
    return (unsigned short)r;
}
__device__ __forceinline__ float bf2f(unsigned short s) {
    union { unsigned int u; float f; } x; x.u = ((unsigned int)s) << 16;
    return x.f;
}

// ---------------- CSR build ----------------

__global__ void hist_kernel(const int* __restrict__ col, int* __restrict__ cnt, int e) {
    int i = blockIdx.x * blockDim.x + threadIdx.x;
    if (i < e) atomicAdd(&cnt[col[i]], 1);
}

// scan over M=N+1 elements + fused dinv
__global__ void scan1_kernel(const int* __restrict__ cnt, int* __restrict__ outp,
                             int* __restrict__ bsums, float* __restrict__ dinv,
                             int M, int n) {
    __shared__ int s[256];
    int tid = threadIdx.x;
    int base = blockIdx.x * 1024 + tid * 4;
    int v[4];
#pragma unroll
    for (int j = 0; j < 4; ++j) {
        int idx = base + j;
        v[j] = (idx < n) ? cnt[idx] : 0;
        if (idx < n) dinv[idx] = rsqrtf((float)(v[j] + 1));  // +1 self-loop
    }
    int tot = v[0] + v[1] + v[2] + v[3];
    s[tid] = tot;
    __syncthreads();
    for (int off = 1; off < 256; off <<= 1) {
        int x = (tid >= off) ? s[tid - off] : 0;
        __syncthreads();
        s[tid] += x;
        __syncthreads();
    }
    int run = (tid == 0) ? 0 : s[tid - 1];
#pragma unroll
    for (int j = 0; j < 4; ++j) {
        int idx = base + j;
        if (idx < M) outp[idx] = run;
        run += v[j];
    }
    if (tid == 255) bsums[blockIdx.x] = s[255];
}

__global__ void scan2_kernel(int* bsums, int nb) {
    if (threadIdx.x == 0 && blockIdx.x == 0) {
        int acc = 0;
        for (int i = 0; i < nb; ++i) { int v = bsums[i]; bsums[i] = acc; acc += v; }
    }
}

__global__ void scan3_kernel(int* __restrict__ outp, const int* __restrict__ bsums, int M) {
    int i = blockIdx.x * blockDim.x + threadIdx.x;
    if (i < M) outp[i] += bsums[i >> 10];
}

__global__ void place_kernel(const int* __restrict__ row, const int* __restrict__ col,
                             const float* __restrict__ dinv, const int* __restrict__ rp,
                             int* __restrict__ fill, int2* __restrict__ csr, int e) {
    int i = blockIdx.x * blockDim.x + threadIdx.x;
    if (i < e) {
        int r = row[i], c = col[i];
        int pos = atomicAdd(&fill[c], 1);
        int idx = rp[c] + pos;
        csr[idx] = make_int2(r, __float_as_int(dinv[r] * dinv[c]));
    }
}

// ---------------- weight transpose+convert: Wt[m][n][k] = bf16(Wsrc_m[k][n]) ----------------
__global__ void wconv_kernel(const float* __restrict__ W_enc, const float* __restrict__ W,
                             unsigned short* __restrict__ Wt) {
    int i = blockIdx.x * blockDim.x + threadIdx.x;
    if (i >= 5 * 16384) return;
    int m = i >> 14;
    int r = (i >> 7) & 127;  // dest row = n
    int k = i & 127;         // dest col = k
    const float* src = (m == 0) ? W_enc : (W + (size_t)(m - 1) * 16384);
    Wt[i] = f2bf(src[k * 128 + r]);
}

// ---------------- MFMA GEMM: C[n x 128] = A[n x 128] @ W[128 x 128] (+bias), C bf16 ----------------
// AMODE: 0 = fp32 A, 1 = bf16 A, 2 = fp32 A with fused BN(scale,shift)+ReLU
template <int AMODE>
__global__ __launch_bounds__(256) void gemm128_mfma(const void* __restrict__ Ap,
                                                    const unsigned short* __restrict__ Wt,
                                                    const float* __restrict__ bias,
                                                    const float* __restrict__ bnp,
                                                    unsigned short* __restrict__ Cp,
                                                    int nrows) {
    int wave = threadIdx.x >> 6;
    int lane = threadIdx.x & 63;
    int r16 = lane & 15;
    int kg = lane >> 4;
    int rowBase = blockIdx.x * 64 + wave * 16;
    int row = rowBase + r16;
    bool valid = row < nrows;

    bf16x8 afr[4];
#pragma unroll
    for (int s = 0; s < 4; ++s) {
        bf16x8 tt = {};
        int c0 = s * 32 + kg * 8;
        if constexpr (AMODE == 1) {
            const unsigned short* A = (const unsigned short*)Ap;
            if (valid) tt = *(const bf16x8*)&A[(size_t)row * 128 + c0];
        } else if constexpr (AMODE == 0) {
            const float* A = (const float*)Ap;
            if (valid) {
                const float* p = &A[(size_t)row * 128 + c0];
                float4 u0 = *(const float4*)p;
                float4 u1 = *(const float4*)(p + 4);
                tt[0] = (short)f2bf(u0.x); tt[1] = (short)f2bf(u0.y);
                tt[2] = (short)f2bf(u0.z); tt[3] = (short)f2bf(u0.w);
                tt[4] = (short)f2bf(u1.x); tt[5] = (short)f2bf(u1.y);
                tt[6] = (short)f2bf(u1.z); tt[7] = (short)f2bf(u1.w);
            }
        } else {
            const float* A = (const float*)Ap;
            if (valid) {
                const float* p = &A[(size_t)row * 128 + c0];
                float4 u0 = *(const float4*)p;
                float4 u1 = *(const float4*)(p + 4);
                float4 s0 = *(const float4*)&bnp[c0];
                float4 s1 = *(const float4*)&bnp[c0 + 4];
                float4 h0 = *(const float4*)&bnp[128 + c0];
                float4 h1 = *(const float4*)&bnp[128 + c0 + 4];
                tt[0] = (short)f2bf(fmaxf(u0.x * s0.x + h0.x, 0.f));
                tt[1] = (short)f2bf(fmaxf(u0.y * s0.y + h0.y, 0.f));
                tt[2] = (short)f2bf(fmaxf(u0.z * s0.z + h0.z, 0.f));
                tt[3] = (short)f2bf(fmaxf(u0.w * s0.w + h0.w, 0.f));
                tt[4] = (short)f2bf(fmaxf(u1.x * s1.x + h1.x, 0.f));
                tt[5] = (short)f2bf(fmaxf(u1.y * s1.y + h1.y, 0.f));
                tt[6] = (short)f2bf(fmaxf(u1.z * s1.z + h1.z, 0.f));
                tt[7] = (short)f2bf(fmaxf(u1.w * s1.w + h1.w, 0.f));
            }
        }
        afr[s] = tt;
    }

    f32x4 acc[8];
#pragma unroll
    for (int n = 0; n < 8; ++n) acc[n] = (f32x4){0.f, 0.f, 0.f, 0.f};

#pragma unroll
    for (int n = 0; n < 8; ++n) {
        const unsigned short* wp = &Wt[(size_t)(n * 16 + r16) * 128 + kg * 8];
#pragma unroll
        for (int s = 0; s < 4; ++s) {
            bf16x8 bfr = *(const bf16x8*)&wp[s * 32];
            acc[n] = __builtin_amdgcn_mfma_f32_16x16x32_bf16(afr[s], bfr, acc[n], 0, 0, 0);
        }
    }

    // C/D: lane holds rows kg*4+i, col r16 (within tile)
#pragma unroll
    for (int n = 0; n < 8; ++n) {
        int col = n * 16 + r16;
        float bv = bias ? bias[col] : 0.f;
#pragma unroll
        for (int i = 0; i < 4; ++i) {
            int orow = rowBase + kg * 4 + i;
            if (orow < nrows)
                Cp[(size_t)orow * 128 + col] = f2bf(acc[n][i] + bv);
        }
    }
}

// ---------------- Aggregation: agg[i] = b + dinv_i^2 * t[i] + sum_e w_e * t[src_e] ----------------
__global__ __launch_bounds__(256) void aggregate_kernel(const unsigned short* __restrict__ t,
                                                        const int* __restrict__ rp,
                                                        const int2* __restrict__ csr,
                                                        const float* __restrict__ dinv,
                                                        const float* __restrict__ bvec,
                                                        float* __restrict__ agg, int n) {
    int wid = blockIdx.x * 4 + (threadIdx.x >> 6);
    int lane = threadIdx.x & 63;
    if (wid >= n) return;
    int c = lane * 2;
    float di = dinv[wid];
    float sw = di * di;
    unsigned int u = *(const unsigned int*)&t[(size_t)wid * 128 + c];
    float2 acc;
    acc.x = sw * bf2f((unsigned short)(u & 0xffff)) + bvec[c];
    acc.y = sw * bf2f((unsigned short)(u >> 16)) + bvec[c + 1];
    int e = rp[wid], e1 = rp[wid + 1];
    for (; e + 3 < e1; e += 4) {
        int2 ew0 = csr[e], ew1 = csr[e + 1], ew2 = csr[e + 2], ew3 = csr[e + 3];
        unsigned int u0 = *(const unsigned int*)&t[(size_t)ew0.x * 128 + c];
        unsigned int u1 = *(const unsigned int*)&t[(size_t)ew1.x * 128 + c];
        unsigned int u2 = *(const unsigned int*)&t[(size_t)ew2.x * 128 + c];
        unsigned int u3 = *(const unsigned int*)&t[(size_t)ew3.x * 128 + c];
        float w0 = __int_as_float(ew0.y), w1 = __int_as_float(ew1.y);
        float w2 = __int_as_float(ew2.y), w3 = __int_as_float(ew3.y);
        acc.x += w0 * bf2f((unsigned short)(u0 & 0xffff)) + w1 * bf2f((unsigned short)(u1 & 0xffff));
        acc.y += w0 * bf2f((unsigned short)(u0 >> 16)) + w1 * bf2f((unsigned short)(u1 >> 16));
        acc.x += w2 * bf2f((unsigned short)(u2 & 0xffff)) + w3 * bf2f((unsigned short)(u3 & 0xffff));
        acc.y += w2 * bf2f((unsigned short)(u2 >> 16)) + w3 * bf2f((unsigned short)(u3 >> 16));
    }
    for (; e < e1; ++e) {
        int2 ew = csr[e];
        unsigned int u0 = *(const unsigned int*)&t[(size_t)ew.x * 128 + c];
        float w0 = __int_as_float(ew.y);
        acc.x += w0 * bf2f((unsigned short)(u0 & 0xffff));
        acc.y += w0 * bf2f((unsigned short)(u0 >> 16));
    }
    *(float2*)&agg[(size_t)wid * 128 + c] = acc;
}

// ---------------- BatchNorm stats: block-private partials + last-block finalize ----------------
// No data atomics: each block plain-stores its 512-float partial (256 sums + 256 sumsqs);
// one counter atomic per block; last block does coalesced reduce + writes bnp. Deterministic.
#define BN_BLOCKS 256
__global__ __launch_bounds__(512) void bn_stats_kernel(const float* __restrict__ agg,
                                                       float* __restrict__ partials,
                                                       int* __restrict__ counter,
                                                       const float* __restrict__ gamma,
                                                       const float* __restrict__ beta,
                                                       float* __restrict__ bnp, int n) {
    int tid = threadIdx.x;
    int c4 = tid & 31, rs = tid >> 5;  // 32 channel-quads x 16 row-streams
    f32x4 s = {0.f, 0.f, 0.f, 0.f}, q = {0.f, 0.f, 0.f, 0.f};
    for (int r = blockIdx.x * 16 + rs; r < n; r += BN_BLOCKS * 16) {
        f32x4 v = *(const f32x4*)&agg[(size_t)r * 128 + c4 * 4];
        s += v;
        q += v * v;
    }
    __shared__ f32x4 ls[512], lq[512];
    __shared__ int lastflag;
    ls[tid] = s;
    lq[tid] = q;
    __syncthreads();
    if (tid < 32) {
        f32x4 ss = ls[tid], qq = lq[tid];
#pragma unroll
        for (int j = 1; j < 16; ++j) { ss += ls[tid + 32 * j]; qq += lq[tid + 32 * j]; }
        float* pb = partials + (size_t)blockIdx.x * 512;
        *(f32x4*)&pb[tid * 4] = ss;
        *(f32x4*)&pb[256 + tid * 4] = qq;
    }
    __threadfence();
    __syncthreads();
    if (tid == 0) lastflag = (atomicAdd(counter, 1) == BN_BLOCKS - 1);
    __syncthreads();
    if (!lastflag) return;

    // coalesced reduce: thread t sums partials[b*512 + t] over all blocks
    float acc = 0.f;
#pragma unroll 8
    for (int bb = 0; bb < BN_BLOCKS; ++bb) acc += partials[(size_t)bb * 512 + tid];
    __shared__ float red[512];
    red[tid] = acc;
    __syncthreads();
    if (tid < 128) {
        float fn = (float)n;
        float mean = red[tid] / fn;
        float var = fmaxf(red[256 + tid] / fn - mean * mean, 0.f);
        float sc = gamma[tid] * rsqrtf(var + BN_EPS);
        bnp[tid] = sc;
        bnp[128 + tid] = beta[tid] - mean * sc;
        if (tid == 0) *counter = 0;  // self-reset for next layer / replay
    }
}

// ---------------- Pool (BN+ReLU fused) + classifier, one block per graph ----------------
__global__ __launch_bounds__(256) void pool_cls_kernel(const float* __restrict__ agg,
                                                       const float* __restrict__ bnp,
                                                       const int* __restrict__ batch,
                                                       const float* __restrict__ Wc,
                                                       const float* __restrict__ bc,
                                                       float* __restrict__ out, int n) {
    int b = blockIdx.x;  // graph id, 0..NB-1
    int tid = threadIdx.x;
    // row range of graph b in sorted batch
    int lo = 0, hi = n;
    while (lo < hi) { int mid = (lo + hi) >> 1; if (batch[mid] < b) lo = mid + 1; else hi = mid; }
    int start = lo;
    hi = n;
    while (lo < hi) { int mid = (lo + hi) >> 1; if (batch[mid] <= b) lo = mid + 1; else hi = mid; }
    int end = lo;

    int c4 = tid & 31, rs = tid >> 5;
    f32x4 sc = *(const f32x4*)&bnp[c4 * 4];
    f32x4 sh = *(const f32x4*)&bnp[128 + c4 * 4];
    f32x4 acc = {0.f, 0.f, 0.f, 0.f};
    for (int r = start + rs; r < end; r += 8) {
        f32x4 v = *(const f32x4*)&agg[(size_t)r * 128 + c4 * 4];
        f32x4 y = v * sc + sh;
#pragma unroll
        for (int k = 0; k < 4; ++k) y[k] = fmaxf(y[k], 0.f);
        acc += y;
    }
    __shared__ f32x4 ls[256];
    __shared__ float g[128];
    ls[tid] = acc;
    __syncthreads();
    if (tid < 32) {
        f32x4 ss = ls[tid];
#pragma unroll
        for (int j = 1; j < 8; ++j) ss += ls[tid + 32 * j];
        float invc = 1.0f / fmaxf((float)(end - start), 1.0f);
#pragma unroll
        for (int k = 0; k < 4; ++k) g[tid * 4 + k] = ss[k] * invc;
    }
    __syncthreads();
    if (tid < NO) {
        float s = bc[tid];
        for (int c = 0; c < 128; ++c) s += g[c] * Wc[c * NO + tid];
        out[b * NO + tid] = s;
    }
}

// ---------------- host launch ----------------
extern "C" void kernel_launch(void* const* d_in, const int* in_sizes, int n_in,
                              void* d_out, int out_size, void* d_ws, size_t ws_size,
                              hipStream_t stream) {
    const float* x      = (const float*)d_in[0];
    const int*   eidx   = (const int*)d_in[1];
    const int*   batch  = (const int*)d_in[2];
    const float* W_enc  = (const float*)d_in[3];
    const float* b_enc  = (const float*)d_in[4];
    const float* W      = (const float*)d_in[5];
    const float* b      = (const float*)d_in[6];
    const float* gamma  = (const float*)d_in[7];
    const float* beta   = (const float*)d_in[8];
    const float* W_cls  = (const float*)d_in[9];
    const float* b_cls  = (const float*)d_in[10];
    float* out = (float*)d_out;

    const int* erow = eidx;
    const int* ecol = eidx + NE;

    // workspace layout
    float* agg      = (float*)d_ws;                      // NN*HD fp32
    float* dinv     = agg + (size_t)NN * HD;             // NN
    float* partials = dinv + NN;                         // BN_BLOCKS*512
    int*   bncnt    = (int*)(partials + BN_BLOCKS * 512);  // 4 ints (1 used)
    float* bnp      = (float*)(bncnt + 4);               // 256
    int2*  csr      = (int2*)(bnp + 256);                // NE int2
    unsigned short* h  = (unsigned short*)(csr + NE);    // NN*HD bf16
    unsigned short* t  = h + (size_t)NN * HD;            // NN*HD bf16
    unsigned short* Wt = t + (size_t)NN * HD;            // 5*16384 bf16
    int* cnt      = (int*)(Wt + 5 * 16384);              // NN
    int* fill     = cnt + NN;                            // NN (adjacent -> one memset)
    int* rp       = fill + NN;                           // NN+1
    int* bsums    = rp + NN + 1;                         // 64

    hipMemsetAsync(cnt, 0, 2 * NN * sizeof(int), stream);
    hipMemsetAsync(bncnt, 0, 4 * sizeof(int), stream);

    // CSR build (once; reused across layers)
    hist_kernel<<<(NE + 255) / 256, 256, 0, stream>>>(ecol, cnt, NE);
    int M = NN + 1;
    int nscan = (M + 1023) / 1024;
    scan1_kernel<<<nscan, 256, 0, stream>>>(cnt, rp, bsums, dinv, M, NN);
    scan2_kernel<<<1, 64, 0, stream>>>(bsums, nscan);
    scan3_kernel<<<(M + 255) / 256, 256, 0, stream>>>(rp, bsums, M);
    place_kernel<<<(NE + 255) / 256, 256, 0, stream>>>(erow, ecol, dinv, rp, fill, csr, NE);

    // weights -> bf16 transposed
    wconv_kernel<<<(5 * 16384 + 255) / 256, 256, 0, stream>>>(W_enc, W, Wt);

    int gemmBlocks = (NN + 63) / 64;
    // encoder: x fp32 -> h bf16
    gemm128_mfma<0><<<gemmBlocks, 256, 0, stream>>>(x, Wt, b_enc, nullptr, h, NN);

    for (int l = 0; l < NL; ++l) {
        if (l == 0)
            gemm128_mfma<1><<<gemmBlocks, 256, 0, stream>>>(
                h, Wt + (size_t)(l + 1) * 16384, nullptr, nullptr, t, NN);
        else
            gemm128_mfma<2><<<gemmBlocks, 256, 0, stream>>>(
                agg, Wt + (size_t)(l + 1) * 16384, nullptr, bnp, t, NN);
        aggregate_kernel<<<(NN + 3) / 4, 256, 0, stream>>>(t, rp, csr, dinv,
                                                           b + (size_t)l * HD, agg, NN);
        bn_stats_kernel<<<BN_BLOCKS, 512, 0, stream>>>(agg, partials, bncnt,
                                                       gamma + (size_t)l * HD,
                                                       beta + (size_t)l * HD, bnp, NN);
    }

    pool_cls_kernel<<<NB, 256, 0, stream>>>(agg, bnp, batch, W_cls, b_cls, out, NN);
}